// Round 9
// baseline (270.574 us; speedup 1.0000x reference)
//
#include <hip/hip_runtime.h>

// PixelPropagationModule  out = gamma * (softmax(qk^T) @ v^T)^T + x
// B=8, C=256, CI=64, N=3136 (56x56), fp32 in/out.
// R8: fixes R7's j-coverage bug (R7 attended only half the keys: 49 steps
//     of JT=32 = 1568 j; masked by softmax self-normalization + tolerance).
//     attn redesign: wave = 32 q (2 A-frags, V frags reused 2x) x 128 ch;
//     block = 64 q x 256 ch; JS=4 correct split (25/25/24/24 of 98 steps),
//     grid 1568. V staged pre-permuted via two b64 global loads so the LDS
//     write is ONE contiguous b128 (bank-minimal write AND read). Double
//     buffer -> 1 barrier/step; V and K both register-prefetched for step+1.
//     proj: PN=32 (grid 784, was 392).

constexpr int B_  = 8;
constexpr int C_  = 256;
constexpr int CI_ = 64;
constexpr int N_  = 3136;
constexpr int JS  = 4;        // attn j-split
constexpr int JT  = 32;       // attn j per step
constexpr int VSP = 40;       // V LDS row pitch (ushorts) = 80 B (16B-mult, bank-minimal)
constexpr int PN  = 32;       // proj pixel tile
constexpr int XSP = C_ + 8;   // proj LDS row pitch

typedef __attribute__((ext_vector_type(8))) short short8;   // 8 bf16 (4 VGPR)
typedef __attribute__((ext_vector_type(4))) float f32x4;

static __device__ inline ushort f2b(float f) {               // fp32 -> bf16 (RNE)
    unsigned u = __float_as_uint(f);
    return (ushort)((u + 0x7fffu + ((u >> 16) & 1u)) >> 16);
}
static __device__ inline float b2f(ushort h) {
    return __uint_as_float(((unsigned)h) << 16);
}

// blocks [0, B_*196): x[B][C][N] f32 -> xT[B][N][C] bf16 (LDS transpose)
// blocks [B_*196, +256): Wq/Wk -> wqk[128][256], Wv -> wv[256][256] bf16
__global__ __launch_bounds__(256)
void pre_kernel(const float* __restrict__ x,
                const float* __restrict__ Wq, const float* __restrict__ Wk,
                const float* __restrict__ Wv,
                ushort* __restrict__ xT, ushort* __restrict__ wqk, ushort* __restrict__ wv)
{
    __shared__ float ts[64][65];
    const int bx  = blockIdx.x;
    const int tid = threadIdx.x;

    if (bx >= B_ * 196) {                            // weight convert
        int i = (bx - B_ * 196) * 256 + tid;
        if (i < 16384)      wqk[i] = f2b(Wq[i]);
        else if (i < 32768) wqk[i] = f2b(Wk[i - 16384]);
        wv[i] = f2b(Wv[i]);
        return;
    }

    const int b  = bx / 196;
    const int rm = bx % 196;
    const int n0 = (rm >> 2) * 64;
    const int c0 = (rm & 3) * 64;

    const float* src = x + ((size_t)b * C_ + c0) * N_ + n0;
    #pragma unroll
    for (int rep = 0; rep < 16; rep++) {             // 4096 floats in
        int e = rep * 256 + tid;
        int c = e >> 6, n = e & 63;
        ts[c][n] = src[(size_t)c * N_ + n];
    }
    __syncthreads();
    ushort* dst = xT + ((size_t)b * N_ + n0) * C_ + c0;
    #pragma unroll
    for (int rep = 0; rep < 8; rep++) {              // 2048 ushort2 out
        int e = rep * 256 + tid;
        int n = e >> 5, c2 = (e & 31) * 2;
        ushort2 o;
        o.x = f2b(ts[c2][n]);
        o.y = f2b(ts[c2 + 1][n]);
        *(ushort2*)(dst + (size_t)n * C_ + c2) = o;
    }
}

__global__ __launch_bounds__(256)
void proj_kernel(const ushort* __restrict__ xT, const ushort* __restrict__ wqk,
                 const ushort* __restrict__ wv,
                 const float* __restrict__ bq, const float* __restrict__ bk,
                 const float* __restrict__ bv,
                 ushort* __restrict__ qb, ushort* __restrict__ kb, ushort* __restrict__ vt)
{
    __shared__ ushort xs[PN][XSP];        // 16896 B
    const int b   = blockIdx.x / 98;
    const int n0  = (blockIdx.x % 98) * PN;
    const int tid = threadIdx.x;
    const int w    = tid >> 6;
    const int lane = tid & 63;
    const int m16  = lane & 15;
    const int quad = lane >> 4;

    // stage xT tile [32 pixels][256 c] bf16
    {
        const ushort* src = xT + ((size_t)b * N_ + n0) * C_;
        #pragma unroll
        for (int rep = 0; rep < 4; rep++) {
            int e = rep * 256 + tid;
            int row = e >> 5, ch = (e & 31) * 8;
            *(short8*)&xs[row][ch] = *(const short8*)(src + (size_t)row * C_ + ch);
        }
    }
    __syncthreads();

    // ---- QK GEMM: C[o][pixel]; waves 0,1 -> Q halves, 2,3 -> K halves ----
    {
        f32x4 acc[2][2];
        #pragma unroll
        for (int mt = 0; mt < 2; mt++)
            #pragma unroll
            for (int nt = 0; nt < 2; nt++) acc[mt][nt] = (f32x4){0.f, 0.f, 0.f, 0.f};

        #pragma unroll
        for (int kk = 0; kk < 8; kk++) {
            short8 af[2];
            #pragma unroll
            for (int mt = 0; mt < 2; mt++)   // A[m=o][k=c] = wqk row (L2-hot)
                af[mt] = *(const short8*)(wqk + (size_t)(w * 32 + mt * 16 + m16) * C_ + kk * 32 + quad * 8);
            #pragma unroll
            for (int nt = 0; nt < 2; nt++) {
                short8 bf = *(const short8*)&xs[nt * 16 + m16][kk * 32 + quad * 8];  // B[k=c][n=pix]
                #pragma unroll
                for (int mt = 0; mt < 2; mt++)
                    acc[mt][nt] = __builtin_amdgcn_mfma_f32_16x16x32_bf16(af[mt], bf, acc[mt][nt], 0, 0, 0);
            }
        }
        const float* bias = (w < 2) ? bq : bk;
        ushort* dst = (w < 2) ? qb : kb;
        const int obase = (w & 1) * 32;
        #pragma unroll
        for (int mt = 0; mt < 2; mt++) {
            f32x4 bs = *(const f32x4*)(bias + obase + mt * 16 + quad * 4);
            #pragma unroll
            for (int nt = 0; nt < 2; nt++) {
                ushort4 pk;
                pk.x = f2b(acc[mt][nt][0] + bs[0]);
                pk.y = f2b(acc[mt][nt][1] + bs[1]);
                pk.z = f2b(acc[mt][nt][2] + bs[2]);
                pk.w = f2b(acc[mt][nt][3] + bs[3]);
                *(ushort4*)(dst + ((size_t)b * N_ + n0 + nt * 16 + m16) * CI_ + obase + mt * 16 + quad * 4) = pk;
            }
        }
    }

    // ---- V GEMM: C[pixel][o]; wave w -> channels w*64..w*64+63 ----
    {
        f32x4 vacc[2][4];
        #pragma unroll
        for (int mt = 0; mt < 2; mt++)
            #pragma unroll
            for (int nt = 0; nt < 4; nt++) vacc[mt][nt] = (f32x4){0.f, 0.f, 0.f, 0.f};

        #pragma unroll
        for (int kk = 0; kk < 8; kk++) {
            short8 af[2];
            #pragma unroll
            for (int mt = 0; mt < 2; mt++)   // A[m=pix][k=c] from LDS
                af[mt] = *(const short8*)&xs[mt * 16 + m16][kk * 32 + quad * 8];
            #pragma unroll
            for (int nt = 0; nt < 4; nt++) {
                short8 bf = *(const short8*)(wv + (size_t)(w * 64 + nt * 16 + m16) * C_ + kk * 32 + quad * 8);
                #pragma unroll
                for (int mt = 0; mt < 2; mt++)
                    vacc[mt][nt] = __builtin_amdgcn_mfma_f32_16x16x32_bf16(af[mt], bf, vacc[mt][nt], 0, 0, 0);
            }
        }
        #pragma unroll
        for (int nt = 0; nt < 4; nt++) {
            int c = w * 64 + nt * 16 + m16;
            float bvc = bv[c];
            #pragma unroll
            for (int mt = 0; mt < 2; mt++) {
                ushort4 pk;
                pk.x = f2b(vacc[mt][nt][0] + bvc);
                pk.y = f2b(vacc[mt][nt][1] + bvc);
                pk.z = f2b(vacc[mt][nt][2] + bvc);
                pk.w = f2b(vacc[mt][nt][3] + bvc);
                *(ushort4*)(vt + ((size_t)b * C_ + c) * N_ + n0 + mt * 16 + quad * 4) = pk;
            }
        }
    }
}

// grid B_*49*JS: block (b, 64q tile t, js). Wave w: q-half (w&1) -> 32 q as
// 2 A-frag groups; ch-half (w>>1) -> 128 ch (8 ct). S^T = K*Q^T, exp in-reg,
// pa[qg] is a PV A-frag under k-perm pi(quad*8+idx) = (idx<4 ? quad*4+idx :
// 16+quad*4+idx-4). V staged pre-permuted: thread loads the two j-half b64s
// so its 16B LDS write at vs[c][s*8] is contiguous b128. Dbuf, 1 barrier/
// step; V+K register-prefetched. Partial O bf16 [b][js][c][i], partial l f32.
__global__ __launch_bounds__(256, 3)
void attn_kernel(const ushort* __restrict__ qb, const ushort* __restrict__ kb,
                 const ushort* __restrict__ vt,
                 ushort* __restrict__ op, float* __restrict__ lp)
{
    __shared__ __align__(16) ushort vs[2][C_][VSP];   // 40960 B

    const int bx   = blockIdx.x;
    const int js   = bx & (JS - 1);
    const int t    = (bx >> 2) % 49;
    const int b    = bx / (49 * JS);
    const int tid  = threadIdx.x;
    const int w    = tid >> 6;
    const int lane = tid & 63;
    const int m16  = lane & 15;
    const int quad = lane >> 4;
    const int i0   = t * 64 + (w & 1) * 32;           // this wave's 32 queries
    const int ch0  = (w >> 1) * 128;                  // this wave's 128 channels

    const int steps = (js < 2) ? 25 : 24;             // 25+25+24+24 = 98
    const int jbase = ((js < 2) ? js * 25 : 50 + (js - 2) * 24) * JT;

    const ushort* vtb = vt + (size_t)b * C_ * N_;
    const ushort* kbb = kb + (size_t)b * N_ * CI_;

    // Q B-frags (n=i side), loaded once per q-group: B[k=o][n=i] = q[i][o]
    short8 qf[2][2];
    #pragma unroll
    for (int qg = 0; qg < 2; qg++) {
        const ushort* qbase = qb + ((size_t)b * N_ + i0 + qg * 16 + m16) * CI_;
        qf[qg][0] = *(const short8*)(qbase + quad * 8);
        qf[qg][1] = *(const short8*)(qbase + 32 + quad * 8);
    }

    f32x4 O[2][8];
    #pragma unroll
    for (int qg = 0; qg < 2; qg++)
        #pragma unroll
        for (int ct = 0; ct < 8; ct++) O[qg][ct] = (f32x4){0.f, 0.f, 0.f, 0.f};
    float lsum[2] = {0.f, 0.f};

    // V staging: thread -> rows {p*64+sc}, j-chunk s. Loads j0+s*4(+0..3) and
    // j0+16+s*4(+0..3) as two b64; writes one b128 at vs[c][s*8] (pre-permuted).
    const int sc = tid >> 2;
    const int s4 = (tid & 3) * 4;
    const int sp = (tid & 3) * 8;

    uint2 vr[4][2];
    #define VLOAD(J0)                                                           \
        {                                                                       \
            _Pragma("unroll")                                                   \
            for (int p = 0; p < 4; p++) {                                       \
                const ushort* r = vtb + (size_t)(p * 64 + sc) * N_ + (J0);      \
                vr[p][0] = *(const uint2*)(r + s4);                             \
                vr[p][1] = *(const uint2*)(r + 16 + s4);                        \
            }                                                                   \
        }
    #define VCOMMIT(BUF)                                                        \
        {                                                                       \
            _Pragma("unroll")                                                   \
            for (int p = 0; p < 4; p++) {                                       \
                uint4 t4;                                                       \
                t4.x = vr[p][0].x; t4.y = vr[p][0].y;                           \
                t4.z = vr[p][1].x; t4.w = vr[p][1].y;                           \
                *(uint4*)&vs[BUF][p * 64 + sc][sp] = t4;                        \
            }                                                                   \
        }
    #define KLOAD(DST, J0)                                                      \
        {                                                                       \
            _Pragma("unroll")                                                   \
            for (int h = 0; h < 2; h++) {                                       \
                const ushort* kr = kbb + (size_t)((J0) + h * 16 + m16) * CI_;   \
                DST[h * 2 + 0] = *(const short8*)(kr + quad * 8);               \
                DST[h * 2 + 1] = *(const short8*)(kr + 32 + quad * 8);          \
            }                                                                   \
        }

    short8 kc[4];
    KLOAD(kc, jbase)
    VLOAD(jbase)
    VCOMMIT(0)
    __syncthreads();

    int buf = 0;
    for (int st = 0; st < steps; st++) {
        const int j0 = jbase + st * JT;
        const bool more = (st + 1 < steps);
        short8 kn[4];
        if (more) { VLOAD(j0 + JT) KLOAD(kn, j0 + JT) }

        // ---- S^T = K Q^T (2 j16-halves x 2 q-groups); exp -> pa frags ----
        short8 pa[2];
        #pragma unroll
        for (int h = 0; h < 2; h++) {
            f32x4 T0 = (f32x4){0.f, 0.f, 0.f, 0.f};
            f32x4 T1 = (f32x4){0.f, 0.f, 0.f, 0.f};
            T0 = __builtin_amdgcn_mfma_f32_16x16x32_bf16(kc[h * 2 + 0], qf[0][0], T0, 0, 0, 0);
            T1 = __builtin_amdgcn_mfma_f32_16x16x32_bf16(kc[h * 2 + 0], qf[1][0], T1, 0, 0, 0);
            T0 = __builtin_amdgcn_mfma_f32_16x16x32_bf16(kc[h * 2 + 1], qf[0][1], T0, 0, 0, 0);
            T1 = __builtin_amdgcn_mfma_f32_16x16x32_bf16(kc[h * 2 + 1], qf[1][1], T1, 0, 0, 0);
            #pragma unroll
            for (int r = 0; r < 4; r++) {
                float p0 = __expf(T0[r] - 12.0f);    // static shift: |s| bounded
                float p1 = __expf(T1[r] - 12.0f);
                lsum[0] += p0;
                lsum[1] += p1;
                pa[0][h * 4 + r] = (short)f2b(p0);
                pa[1][h * 4 + r] = (short)f2b(p1);
            }
        }

        // ---- PV: each V B-frag (1 b128) feeds BOTH q-groups ----
        #pragma unroll
        for (int ct = 0; ct < 8; ct++) {
            short8 vf = *(const short8*)&vs[buf][ch0 + ct * 16 + m16][quad * 8];
            O[0][ct] = __builtin_amdgcn_mfma_f32_16x16x32_bf16(pa[0], vf, O[0][ct], 0, 0, 0);
            O[1][ct] = __builtin_amdgcn_mfma_f32_16x16x32_bf16(pa[1], vf, O[1][ct], 0, 0, 0);
        }

        if (more) VCOMMIT(buf ^ 1)
        __syncthreads();
        if (more) {
            kc[0] = kn[0]; kc[1] = kn[1]; kc[2] = kn[2]; kc[3] = kn[3];
        }
        buf ^= 1;
    }
    #undef VLOAD
    #undef VCOMMIT
    #undef KLOAD

    // ---- in-wave l reduction over quads; ch-half 0 waves store ----
    #pragma unroll
    for (int qg = 0; qg < 2; qg++) {
        float v = lsum[qg];
        v += __shfl_xor(v, 16);
        v += __shfl_xor(v, 32);
        if ((w >> 1) == 0 && lane < 16)
            lp[(size_t)(b * JS + js) * N_ + i0 + qg * 16 + lane] = v;
    }

    // ---- store bf16 partial O: op[b][js][c][i] ----
    ushort* opb = op + (size_t)(b * JS + js) * C_ * N_;
    #pragma unroll
    for (int qg = 0; qg < 2; qg++)
        #pragma unroll
        for (int ct = 0; ct < 8; ct++) {
            ushort4 pk;
            pk.x = f2b(O[qg][ct][0]);
            pk.y = f2b(O[qg][ct][1]);
            pk.z = f2b(O[qg][ct][2]);
            pk.w = f2b(O[qg][ct][3]);
            *(ushort4*)(opb + (size_t)(ch0 + ct * 16 + m16) * N_ + i0 + qg * 16 + quad * 4) = pk;
        }
}

// grid 6272: thread -> (b, c, 4 consecutive i). out = gamma*Σp/Σl + x
__global__ __launch_bounds__(256)
void reduce_kernel(const ushort* __restrict__ op, const float* __restrict__ lp,
                   const float* __restrict__ x, const float* __restrict__ gamma_p,
                   float* __restrict__ out)
{
    const int g  = blockIdx.x * 256 + threadIdx.x;   // B*C*N/4 total
    const int i4 = g % (N_ / 4);
    const int c  = (g / (N_ / 4)) % C_;
    const int b  = g / ((N_ / 4) * C_);
    const size_t io = (size_t)i4 * 4;
    const float g0 = gamma_p[0];

    f32x4 acc = (f32x4){0.f, 0.f, 0.f, 0.f};
    f32x4 lt  = (f32x4){0.f, 0.f, 0.f, 0.f};
    #pragma unroll
    for (int js = 0; js < JS; js++) {
        ushort4 a = *(const ushort4*)(op + ((size_t)(b * JS + js) * C_ + c) * N_ + io);
        f32x4   l = *(const f32x4*)(lp + (size_t)(b * JS + js) * N_ + io);
        acc[0] += b2f(a.x); acc[1] += b2f(a.y); acc[2] += b2f(a.z); acc[3] += b2f(a.w);
        lt += l;
    }

    const size_t xo = ((size_t)b * C_ + c) * N_ + io;
    f32x4 xv = *(const f32x4*)(x + xo);
    f32x4 ov;
    #pragma unroll
    for (int u = 0; u < 4; u++) ov[u] = acc[u] * (g0 / lt[u]) + xv[u];
    *(f32x4*)(out + xo) = ov;
}

extern "C" void kernel_launch(void* const* d_in, const int* in_sizes, int n_in,
                              void* d_out, int out_size, void* d_ws, size_t ws_size,
                              hipStream_t stream)
{
    const float* x  = (const float*)d_in[0];
    const float* Wq = (const float*)d_in[1];
    const float* bq = (const float*)d_in[2];
    const float* Wk = (const float*)d_in[3];
    const float* bk = (const float*)d_in[4];
    const float* Wv = (const float*)d_in[5];
    const float* bv = (const float*)d_in[6];
    const float* gm = (const float*)d_in[7];
    float* out = (float*)d_out;

    ushort* qb   = (ushort*)d_ws;                    // [B][N][CI]  3.2 MB
    ushort* kb   = qb + (size_t)B_ * N_ * CI_;       // [B][N][CI]  3.2 MB
    ushort* vt   = kb + (size_t)B_ * N_ * CI_;       // [B][C][N]  12.8 MB
    ushort* xT   = vt + (size_t)B_ * C_ * N_;        // [B][N][C]  12.8 MB
    ushort* wqk  = xT + (size_t)B_ * N_ * C_;        // [128][256] 64 KB
    ushort* wv   = wqk + 128 * C_;                   // [256][256] 128 KB
    ushort* op   = wv + 256 * C_;                    // [B][JS][C][N] bf16 51.4 MB
    float*  lpf  = (float*)(op + (size_t)B_ * JS * C_ * N_);  // [B][JS][N] 401 KB

    hipLaunchKernelGGL(pre_kernel, dim3(B_ * 196 + 256), dim3(256), 0, stream,
                       x, Wq, Wk, Wv, xT, wqk, wv);
    hipLaunchKernelGGL(proj_kernel, dim3(B_ * 98), dim3(256), 0, stream,
                       xT, wqk, wv, bq, bk, bv, qb, kb, vt);
    hipLaunchKernelGGL(attn_kernel, dim3(B_ * 49 * JS), dim3(256), 0, stream,
                       qb, kb, vt, op, lpf);
    hipLaunchKernelGGL(reduce_kernel, dim3(B_ * C_ * (N_ / 4) / 256), dim3(256), 0, stream,
                       op, lpf, x, gm, out);
}